// Round 6
// baseline (219.323 us; speedup 1.0000x reference)
//
#include <hip/hip_runtime.h>

#define S_LEN 2048
#define NB    2
#define EMB   1024
#define NH    16
#define HD    64

typedef __bf16 bf16_t;
typedef bf16_t bf16x8 __attribute__((ext_vector_type(8)));
typedef bf16_t bf16x4v __attribute__((ext_vector_type(4)));
typedef float  f32x4  __attribute__((ext_vector_type(4)));
typedef float  f32x16 __attribute__((ext_vector_type(16)));

#define L2E 1.44269504f   // log2(e)

// async global->LDS, 16B per lane; LDS dest = wave-uniform base + lane*16
__device__ __forceinline__ void g2l16(const void* g, void* l) {
    auto gp = reinterpret_cast<const unsigned int __attribute__((address_space(1)))*>(
        reinterpret_cast<uintptr_t>(g));
    auto lp = reinterpret_cast<unsigned int __attribute__((address_space(3)))*>(
        reinterpret_cast<uintptr_t>(l));
    __builtin_amdgcn_global_load_lds(gp, lp, 16, 0, 0);
}

// pack two f32 -> one u32 of 2 bf16 (h[0] = a = low address on store)
__device__ __forceinline__ unsigned int pk2(float a, float b) {
    union { unsigned int u; bf16_t h[2]; } r;
    r.h[0] = (bf16_t)a; r.h[1] = (bf16_t)b;
    return r.u;
}

// ---------------------------------------------------------------------------
// Fused fp32 -> bf16 cast of x, w_tor, in_proj_w, out_w (float4 granularity).
// ---------------------------------------------------------------------------
__global__ __launch_bounds__(256) void cast4_f32_bf16(
    const float* __restrict__ s0, bf16_t* __restrict__ d0,
    const float* __restrict__ s1, bf16_t* __restrict__ d1,
    const float* __restrict__ s2, bf16_t* __restrict__ d2,
    const float* __restrict__ s3, bf16_t* __restrict__ d3)
{
    long i = (long)blockIdx.x * 256 + threadIdx.x;
    const float* s; bf16_t* d; long off;
    if (i < 1048576)      { s = s0; d = d0; off = i; }
    else if (i < 1310720) { s = s1; d = d1; off = i - 1048576; }
    else if (i < 2097152) { s = s2; d = d2; off = i - 1310720; }
    else                  { s = s3; d = d3; off = i - 2097152; }
    float4 v = ((const float4*)s)[off];
    bf16x4v o;
    o[0] = (bf16_t)v.x; o[1] = (bf16_t)v.y; o[2] = (bf16_t)v.z; o[3] = (bf16_t)v.w;
    *(bf16x4v*)(d + off * 4) = o;
}

// ---------------------------------------------------------------------------
// bf16 MFMA GEMM, double-buffered prefetch K-loop (1 barrier/iter).
// C(M,N) = A(M,K) @ W(N,K)^T + bias(N). TM=128, TN in {64,128}, BK=32.
// MODE: 0 = fp32 out, 1 = bf16 out. (Used for GEMM1/GEMM3 only now.)
// ---------------------------------------------------------------------------
template<int TN, int MODE>
__global__ __launch_bounds__(256) void gemm_bt_bf16(
    const bf16_t* __restrict__ A, const bf16_t* __restrict__ W,
    const float* __restrict__ bias, void* __restrict__ Cout,
    int M, int N, int K)
{
    constexpr int MB = (TN == 128) ? 4 : 2;
    __shared__ __align__(16) bf16_t As[2][128 * 32];
    __shared__ __align__(16) bf16_t Bs[2][TN * 32];

    const int tid  = threadIdx.x;
    const int lane = tid & 63;
    const int w    = tid >> 6;
    const int lm   = lane & 15;
    const int lq   = lane >> 4;
    const long m0  = (long)blockIdx.y * 128;
    const long n0  = (long)blockIdx.x * TN;
    const int wm0  = (TN == 128) ? (w >> 1) * 64 : w * 32;
    const int wn0  = (TN == 128) ? (w & 1) * 64 : 0;

    f32x4 acc[MB][4];
#pragma unroll
    for (int i = 0; i < MB; ++i)
#pragma unroll
        for (int j = 0; j < 4; ++j) acc[i][j] = (f32x4){0.f, 0.f, 0.f, 0.f};

    auto stage = [&](int k0, int buf) {
        bf16_t* asb = &As[buf][0];
        bf16_t* bsb = &Bs[buf][0];
#pragma unroll
        for (int j = 0; j < 2; ++j) {
            int a   = (w * 2 + j) * 64 + lane;
            int row = a >> 2;
            int c   = (a & 3) ^ ((row >> 1) & 3);
            g2l16(A + (m0 + row) * K + k0 + c * 8, asb + (w * 2 + j) * 512);
        }
#pragma unroll
        for (int j = 0; j < TN / 64; ++j) {
            int a   = (w * (TN / 64) + j) * 64 + lane;
            int row = a >> 2;
            int c   = (a & 3) ^ ((row >> 1) & 3);
            g2l16(W + (n0 + row) * K + k0 + c * 8, bsb + (w * (TN / 64) + j) * 512);
        }
    };

    stage(0, 0);
    for (int k0 = 0; k0 < K; k0 += 32) {
        const int cur = (k0 >> 5) & 1;
        asm volatile("s_waitcnt vmcnt(0)" ::: "memory");
        __syncthreads();
        if (k0 + 32 < K) stage(k0 + 32, cur ^ 1);

        bf16x8 af[MB], bfr[4];
#pragma unroll
        for (int mb = 0; mb < MB; ++mb) {
            int r = wm0 + mb * 16 + lm;
            af[mb] = *(const bf16x8*)&As[cur][r * 32 + ((lq ^ ((r >> 1) & 3)) << 3)];
        }
#pragma unroll
        for (int nb = 0; nb < 4; ++nb) {
            int r = wn0 + nb * 16 + lm;
            bfr[nb] = *(const bf16x8*)&Bs[cur][r * 32 + ((lq ^ ((r >> 1) & 3)) << 3)];
        }
#pragma unroll
        for (int mb = 0; mb < MB; ++mb)
#pragma unroll
            for (int nb = 0; nb < 4; ++nb)
                acc[mb][nb] = __builtin_amdgcn_mfma_f32_16x16x32_bf16(
                    af[mb], bfr[nb], acc[mb][nb], 0, 0, 0);
    }

    // ---- epilogue ----
    float b4[4];
#pragma unroll
    for (int nb = 0; nb < 4; ++nb) b4[nb] = bias[n0 + wn0 + nb * 16 + lm];

#pragma unroll
    for (int mb = 0; mb < MB; ++mb) {
#pragma unroll
        for (int r = 0; r < 4; ++r) {
            long m = m0 + wm0 + mb * 16 + lq * 4 + r;
#pragma unroll
            for (int nb = 0; nb < 4; ++nb) {
                int n   = (int)n0 + wn0 + nb * 16 + lm;
                float v = acc[mb][nb][r] + b4[nb];
                if (MODE == 0) ((float*)Cout)[m * N + n] = v;
                else           ((bf16_t*)Cout)[m * N + n] = (bf16_t)v;
            }
        }
    }
}

// ---------------------------------------------------------------------------
// GEMM2 (qkv projection), 256x256 tile, BK=64, 8 waves, phase-split K-loop —
// plain-HIP port of the verified m201 8-phase structure (1563 TF @4k):
//   * LDS 128 KB dynamic (2 dbuf x (A 32KB + B 32KB)); XOR slot(row,c) =
//     c^(row&7) layout; staging = linear g2l16 dest + inverse-swizzled
//     global source (8 x 128B segments per instr, fully coalesced).
//   * Per K-tile: 4 phases of {8 ds_read_b128 | 4 g2l16 prefetch | s_barrier
//     | setprio(1) | 16 MFMA | setprio(0) | s_barrier}; next tile's A staged
//     at phase 0, B at phase 1 (2-3 phases of HBM-latency cover = max depth
//     with 2 buffers); ONE vmcnt(0)+__syncthreads per K-tile (T4: loads
//     never waited-on right after issue).
//   * Epilogue: qkv head-layout scatter; Q pre-scaled 0.125*log2e; Vt dword
//     pairing (R5). K-accumulation order identical to the 128 kernel.
// Grid 192 blocks (16 m x 12 n, XCD-swizzled m-major), 512 thr.
// ---------------------------------------------------------------------------
__global__ __launch_bounds__(512, 2) void gemm_qkv_256(
    const bf16_t* __restrict__ A, const bf16_t* __restrict__ W,
    const float* __restrict__ bias,
    bf16_t* __restrict__ Qp, bf16_t* __restrict__ Kp, bf16_t* __restrict__ Vtp)
{
    extern __shared__ __align__(16) char smem[];
    bf16_t* AsB = (bf16_t*)smem;               // [2][256*64] bf16 = 64 KB
    bf16_t* BsB = (bf16_t*)(smem + 65536);     // [2][256*64] bf16 = 64 KB

    const int tid  = threadIdx.x;
    const int lane = tid & 63;
    const int w    = tid >> 6;       // 0..7
    const int wr   = w >> 2;         // 0..1  (M half)
    const int wc   = w & 3;          // 0..3  (N quarter)
    const int lm   = lane & 15;
    const int lq   = lane >> 4;
    const int rs8  = lane >> 3;      // 0..7 row-in-group for staging
    const int csw  = (lane & 7) ^ rs8;   // inverse-swizzled k-chunk

    // XCD swizzle: 192 blocks, XCD x owns swz [24x, 24x+24) = 2 full m-rows
    const int bid  = blockIdx.x;
    const int swz  = (bid & 7) * 24 + (bid >> 3);
    const long m0  = (long)(swz / 12) * 256;
    const long n0  = (long)(swz % 12) * 256;

    f32x4 acc[8][4];
#pragma unroll
    for (int i = 0; i < 8; ++i)
#pragma unroll
        for (int j = 0; j < 4; ++j) acc[i][j] = (f32x4){0.f, 0.f, 0.f, 0.f};

    auto stageA = [&](int kt, int buf) {
        bf16_t* dst = AsB + buf * 16384;
        const bf16_t* src = A + (m0 + rs8) * 1024 + kt * 64 + csw * 8;
#pragma unroll
        for (int j = 0; j < 4; ++j) {
            int iA = w * 4 + j;                   // rows [iA*8, iA*8+8)
            g2l16(src + (size_t)iA * 8 * 1024, dst + iA * 512);
        }
    };
    auto stageB = [&](int kt, int buf) {
        bf16_t* dst = BsB + buf * 16384;
        const bf16_t* src = W + (n0 + rs8) * 1024 + kt * 64 + csw * 8;
#pragma unroll
        for (int j = 0; j < 4; ++j) {
            int iB = w * 4 + j;
            g2l16(src + (size_t)iB * 8 * 1024, dst + iB * 512);
        }
    };

    // prologue: tiles 0 and 1 in flight; wait tile 0 (oldest 8 instrs)
    stageA(0, 0); stageB(0, 0);
    stageA(1, 1); stageB(1, 1);
    asm volatile("s_waitcnt vmcnt(8)" ::: "memory");
    __syncthreads();

    for (int t = 0; t < 16; ++t) {
        const int cur = t & 1;
        const bf16_t* Ac = AsB + cur * 16384;
        const bf16_t* Bc = BsB + cur * 16384;
        const bool st = (t >= 1) && (t < 15);    // tile1 staged in prologue

#pragma unroll
        for (int p = 0; p < 4; ++p) {
            const int ks  = p >> 1;              // k-half of BK=64
            const int mbh = p & 1;               // m-half of wave's 128 rows
            bf16x8 af[4], bfq[4];
#pragma unroll
            for (int j = 0; j < 4; ++j) {
                int rowA = wr * 128 + mbh * 64 + j * 16 + lm;
                af[j]  = *(const bf16x8*)&Ac[rowA * 64 + (((ks * 4 + lq) ^ (lm & 7)) * 8)];
                int rowB = wc * 64 + j * 16 + lm;
                bfq[j] = *(const bf16x8*)&Bc[rowB * 64 + (((ks * 4 + lq) ^ (lm & 7)) * 8)];
            }
            if (p == 0 && st) stageA(t + 1, cur ^ 1);
            if (p == 1 && st) stageB(t + 1, cur ^ 1);
            __builtin_amdgcn_s_barrier();
            __builtin_amdgcn_s_setprio(1);
#pragma unroll
            for (int j = 0; j < 4; ++j)
#pragma unroll
                for (int nb = 0; nb < 4; ++nb)
                    acc[mbh * 4 + j][nb] = __builtin_amdgcn_mfma_f32_16x16x32_bf16(
                        af[j], bfq[nb], acc[mbh * 4 + j][nb], 0, 0, 0);
            __builtin_amdgcn_s_setprio(0);
            __builtin_amdgcn_s_barrier();
        }
        // next tile's loads (issued at phases 0-1) are the only outstanding
        asm volatile("s_waitcnt vmcnt(0)" ::: "memory");
        __syncthreads();
    }

    // ---- qkv epilogue ----
    float b4[4];
#pragma unroll
    for (int nb = 0; nb < 4; ++nb) b4[nb] = bias[n0 + wc * 64 + nb * 16 + lm];
    const int sec = (int)(n0 >> 10);             // uniform per block (BN=256)

#pragma unroll
    for (int mb = 0; mb < 8; ++mb) {
        const long mbase = m0 + wr * 128 + mb * 16 + lq * 4;   // even
#pragma unroll
        for (int nb = 0; nb < 4; ++nb) {
            int n    = (int)n0 + wc * 64 + nb * 16 + lm;
            int nloc = n & 1023;
            int h    = nloc >> 6;
            int d    = nloc & 63;
            if (sec == 2) {
                int s0 = (int)(mbase >> 1);
#pragma unroll
                for (int rp = 0; rp < 2; ++rp) {
                    int bh = rp * 16 + h;
                    unsigned int pkv = pk2(acc[mb][nb][rp]     + b4[nb],
                                           acc[mb][nb][rp + 2] + b4[nb]);
                    *(unsigned int*)&Vtp[((size_t)(bh * 64 + d)) * S_LEN + s0] = pkv;
                }
            } else {
#pragma unroll
                for (int r = 0; r < 4; ++r) {
                    long m  = mbase + r;
                    int  s  = (int)(m >> 1), b = (int)(m & 1);
                    int  bh = b * 16 + h;
                    float v = acc[mb][nb][r] + b4[nb];
                    if (sec == 0) {
                        Qp[((size_t)(bh * S_LEN + s)) * 64 + d] =
                            (bf16_t)(v * (0.125f * L2E));
                    } else {
                        Kp[((size_t)(bh * S_LEN + s)) * 64 + d] = (bf16_t)v;
                    }
                }
            }
        }
    }
}

// ---------------------------------------------------------------------------
// MFMA flash attention — R3 configuration (measured 54.5-55.1us, best of
// R0..R5): 256 thr / 4 waves / 32 iters / 2 blocks per CU; P via LDS;
// coalesced staging + XOR slot(row,c)=row*8+(c^(row&7)) K/V layout;
// contiguous P layout [chunk][hi][q]; XCD-aware bh swizzle; setprio.
// Pinned lessons: R1 in-reg-P slower (serial VALU); R2 key-split slower;
// R4 64q/wave (1 wave/SIMD) much slower.
// ---------------------------------------------------------------------------
__global__ __launch_bounds__(256, 2) void attn_mfma(
    const bf16_t* __restrict__ Qb, const bf16_t* __restrict__ Kb,
    const bf16_t* __restrict__ Vtb, bf16_t* __restrict__ O)
{
    __shared__ __align__(16) bf16_t Ks[2][8 * 512];    // 16 KB, swizzled rows
    __shared__ __align__(16) bf16_t Vts[2][8 * 512];   // 16 KB, swizzled rows
    __shared__ __align__(16) bf16_t Ps[4][8 * 256];    // 16 KB, wave-private

    const int tid  = threadIdx.x;
    const int lane = tid & 63;
    const int w    = tid >> 6;
    const int bid  = blockIdx.x;
    // XCD swizzle: XCD x gets blocks {x, x+8, ...} = 4 consecutive bh
    const int bh   = ((bid & 7) << 2) | (bid >> 7);
    const int qt   = (bid >> 3) & 15;
    const int l5   = lane & 31;
    const int hi   = lane >> 5;

    // staging lane geometry: row-within-8-group + inverse-swizzled chunk
    const int rsub = lane >> 3;                  // 0..7
    const int csw  = (lane & 7) ^ rsub;          // chunk this lane fetches
    // fragment-read swizzled chunk offsets (elements), per-lane constant
    int cc[4];
#pragma unroll
    for (int i = 0; i < 4; ++i) cc[i] = ((2 * i + hi) ^ (l5 & 7)) * 8;

    // Q B-frags (B[n=q][k=d]), q = qt*128 + w*32 + l5, held in regs
    const bf16_t* qrow = Qb + ((size_t)bh * S_LEN + qt * 128 + w * 32 + l5) * 64 + hi * 8;
    bf16x8 qf[4];
#pragma unroll
    for (int ds = 0; ds < 4; ++ds) qf[ds] = *(const bf16x8*)(qrow + ds * 16);

    f32x16 oacc[2];
#pragma unroll
    for (int dh = 0; dh < 2; ++dh)
#pragma unroll
        for (int i = 0; i < 16; ++i) oacc[dh][i] = 0.f;
    float plsum = 0.f;

    // coalesced staging: instr i covers rows 8i..8i+7, LDS bytes [1024i,1024i+1024)
    auto stageKV = [&](int kt, int buf) {
        bf16_t* ksb = &Ks[buf][0];
        bf16_t* vsb = &Vts[buf][0];
        const bf16_t* kg = Kb + ((size_t)bh * S_LEN + kt * 64) * 64;
        const bf16_t* vg = Vtb + (size_t)bh * 64 * S_LEN + kt * 64;
#pragma unroll
        for (int j = 0; j < 2; ++j) {
            int i = w * 2 + j;
            g2l16(kg + (size_t)(i * 8 + rsub) * 64 + csw * 8,    ksb + i * 512);
            g2l16(vg + (size_t)(i * 8 + rsub) * S_LEN + csw * 8, vsb + i * 512);
        }
    };

    stageKV(0, 0);
    for (int kt = 0; kt < 32; ++kt) {
        const int cur = kt & 1;
        asm volatile("s_waitcnt vmcnt(0)" ::: "memory");
        __syncthreads();
        if (kt < 31) stageKV(kt + 1, cur ^ 1);

        // ---- S^T = K·Q^T per key half (log2 domain) ----
        f32x16 sacc[2];
        __builtin_amdgcn_s_setprio(1);
#pragma unroll
        for (int kh = 0; kh < 2; ++kh) {
#pragma unroll
            for (int i = 0; i < 16; ++i) sacc[kh][i] = 0.f;
#pragma unroll
            for (int ds = 0; ds < 4; ++ds) {
                bf16x8 kf = *(const bf16x8*)&Ks[cur][(kh * 32 + l5) * 64 + cc[ds]];
                sacc[kh] = __builtin_amdgcn_mfma_f32_32x32x16_bf16(kf, qf[ds], sacc[kh], 0, 0, 0);
            }
        }
        __builtin_amdgcn_s_setprio(0);

        // ---- toroidal bias: only near-diagonal K-tiles ----
        int ktd = (kt - 2 * qt) & 31;
        if (ktd <= 2 || ktd == 31) {
            int q = qt * 128 + w * 32 + l5;
#pragma unroll
            for (int kh = 0; kh < 2; ++kh)
#pragma unroll
                for (int r = 0; r < 16; ++r) {
                    int key  = kt * 64 + kh * 32 + (r & 3) + 8 * (r >> 2) + 4 * hi;
                    int diff = (key - q) & (S_LEN - 1);
                    if (diff <= 1 || diff == S_LEN - 1) sacc[kh][r] += L2E;
                }
        }

        // ---- p = 2^S; b64 writes to conflict-free [chunk][hi][q] layout ----
#pragma unroll
        for (int kh = 0; kh < 2; ++kh)
#pragma unroll
            for (int g = 0; g < 4; ++g) {
                bf16x4v pk;
#pragma unroll
                for (int e = 0; e < 4; ++e) {
                    float p = __builtin_amdgcn_exp2f(sacc[kh][g * 4 + e]);
                    plsum += p;
                    pk[e] = (bf16_t)p;
                }
                // keys kh*32 + 8g + 4hi + e -> chunk kh*4+g, half hi, row q=l5
                *(bf16x4v*)&Ps[w][(kh * 4 + g) * 256 + hi * 128 + l5 * 4] = pk;
            }

        // ---- PV: O[q][d] += P·V (P same-wave, lgkm-ordered) ----
        bf16x8 pf[4];
#pragma unroll
        for (int ks = 0; ks < 4; ++ks) {
            bf16x4v lo = *(const bf16x4v*)&Ps[w][(2 * ks + hi) * 256 + l5 * 4];
            bf16x4v hb = *(const bf16x4v*)&Ps[w][(2 * ks + hi) * 256 + 128 + l5 * 4];
#pragma unroll
            for (int e = 0; e < 4; ++e) { pf[ks][e] = lo[e]; pf[ks][4 + e] = hb[e]; }
        }
        __builtin_amdgcn_s_setprio(1);
#pragma unroll
        for (int dh = 0; dh < 2; ++dh) {
#pragma unroll
            for (int ks = 0; ks < 4; ++ks) {
                bf16x8 vf = *(const bf16x8*)&Vts[cur][(dh * 32 + l5) * 64 + cc[ks]];
                oacc[dh] = __builtin_amdgcn_mfma_f32_32x32x16_bf16(pf[ks], vf, oacc[dh], 0, 0, 0);
            }
        }
        __builtin_amdgcn_s_setprio(0);
    }

    // ---- l: lane + lane^32 hold the two key-halves of row q=l5 ----
    plsum += __shfl_xor(plsum, 32, 64);
    float* Lw = (float*)&Ps[w][0];            // reuse wave-private region
    if (hi == 0) Lw[l5] = plsum;

    float inv16[16];
#pragma unroll
    for (int g = 0; g < 4; ++g) {
        f32x4 lv = *(const f32x4*)&Lw[8 * g + 4 * hi];
#pragma unroll
        for (int e = 0; e < 4; ++e) inv16[g * 4 + e] = 1.0f / lv[e];
    }

    const int b = bh >> 4, h = bh & 15;
#pragma unroll
    for (int dh = 0; dh < 2; ++dh)
#pragma unroll
        for (int r = 0; r < 16; ++r) {
            int qrel = (r & 3) + 8 * (r >> 2) + 4 * hi;
            int s = qt * 128 + w * 32 + qrel;
            O[((size_t)(s * NB + b)) * EMB + h * 64 + dh * 32 + l5] =
                (bf16_t)(oacc[dh][r] * inv16[r]);
        }
}

// ---------------------------------------------------------------------------
// Workspace map (42 MB):
//   [ 0, 8) xb -> reused as Qb | [ 8,10) wtorb | [10,16) ipwb | [16,18) outwb
//   [18,26) xtb -> reused as Ob | [26,34) Kb | [34,42) Vtb (natural cols)
// ---------------------------------------------------------------------------
extern "C" void kernel_launch(void* const* d_in, const int* in_sizes, int n_in,
                              void* d_out, int out_size, void* d_ws, size_t ws_size,
                              hipStream_t stream)
{
    const float* x         = (const float*)d_in[0];
    const float* w_tor     = (const float*)d_in[1];
    const float* b_tor     = (const float*)d_in[2];
    const float* in_proj_w = (const float*)d_in[3];
    const float* in_proj_b = (const float*)d_in[4];
    const float* out_w     = (const float*)d_in[5];
    const float* out_b     = (const float*)d_in[6];
    float* out = (float*)d_out;

    const int M = S_LEN * NB;   // 4096

    char* base = (char*)d_ws;
    bf16_t* xb    = (bf16_t*)(base);
    bf16_t* wtorb = (bf16_t*)(base + ( 8ull << 20));
    bf16_t* ipwb  = (bf16_t*)(base + (10ull << 20));
    bf16_t* outwb = (bf16_t*)(base + (16ull << 20));
    bf16_t* xtb   = (bf16_t*)(base + (18ull << 20));
    bf16_t* Kb    = (bf16_t*)(base + (26ull << 20));
    bf16_t* Vtb   = (bf16_t*)(base + (34ull << 20));
    bf16_t* Qb    = xb;    // alias: xb dead once GEMM1 has run
    bf16_t* Ob    = xtb;   // alias: xtb dead once GEMM2 has run

    // allow 128 KB dynamic LDS for the 256-tile qkv GEMM (m201 structure)
    hipFuncSetAttribute((const void*)gemm_qkv_256,
                        hipFuncAttributeMaxDynamicSharedMemorySize, 131072);

    cast4_f32_bf16<<<dim3(9216), 256, 0, stream>>>(
        x, xb, w_tor, wtorb, in_proj_w, ipwb, out_w, outwb);

    gemm_bt_bf16<64, 1><<<dim3(EMB / 64, M / 128), 256, 0, stream>>>(
        xb, wtorb, b_tor, xtb, M, EMB, EMB);

    gemm_qkv_256<<<dim3(192), 512, 131072, stream>>>(
        xtb, ipwb, in_proj_b, Qb, Kb, Vtb);

    attn_mfma<<<dim3(32 * 16), 256, 0, stream>>>(Qb, Kb, Vtb, Ob);

    gemm_bt_bf16<64, 0><<<dim3(EMB / 64, M / 128), 256, 0, stream>>>(
        Ob, outwb, out_b, out, M, EMB, EMB);
}

// Round 7
// 208.052 us; speedup vs baseline: 1.0542x; 1.0542x over previous
//
#include <hip/hip_runtime.h>

#define S_LEN 2048
#define NB    2
#define EMB   1024
#define NH    16
#define HD    64

typedef __bf16 bf16_t;
typedef bf16_t bf16x8 __attribute__((ext_vector_type(8)));
typedef bf16_t bf16x4v __attribute__((ext_vector_type(4)));
typedef float  f32x4  __attribute__((ext_vector_type(4)));
typedef float  f32x16 __attribute__((ext_vector_type(16)));

#define L2E 1.44269504f   // log2(e)

// async global->LDS, 16B per lane; LDS dest = wave-uniform base + lane*16
__device__ __forceinline__ void g2l16(const void* g, void* l) {
    auto gp = reinterpret_cast<const unsigned int __attribute__((address_space(1)))*>(
        reinterpret_cast<uintptr_t>(g));
    auto lp = reinterpret_cast<unsigned int __attribute__((address_space(3)))*>(
        reinterpret_cast<uintptr_t>(l));
    __builtin_amdgcn_global_load_lds(gp, lp, 16, 0, 0);
}

// pack two f32 -> one u32 of 2 bf16 (h[0] = a = low address on store)
__device__ __forceinline__ unsigned int pk2(float a, float b) {
    union { unsigned int u; bf16_t h[2]; } r;
    r.h[0] = (bf16_t)a; r.h[1] = (bf16_t)b;
    return r.u;
}

// ---------------------------------------------------------------------------
// Fused fp32 -> bf16 cast of x, w_tor, in_proj_w, out_w (float4 granularity).
// ---------------------------------------------------------------------------
__global__ __launch_bounds__(256) void cast4_f32_bf16(
    const float* __restrict__ s0, bf16_t* __restrict__ d0,
    const float* __restrict__ s1, bf16_t* __restrict__ d1,
    const float* __restrict__ s2, bf16_t* __restrict__ d2,
    const float* __restrict__ s3, bf16_t* __restrict__ d3)
{
    long i = (long)blockIdx.x * 256 + threadIdx.x;
    const float* s; bf16_t* d; long off;
    if (i < 1048576)      { s = s0; d = d0; off = i; }
    else if (i < 1310720) { s = s1; d = d1; off = i - 1048576; }
    else if (i < 2097152) { s = s2; d = d2; off = i - 1310720; }
    else                  { s = s3; d = d3; off = i - 2097152; }
    float4 v = ((const float4*)s)[off];
    bf16x4v o;
    o[0] = (bf16_t)v.x; o[1] = (bf16_t)v.y; o[2] = (bf16_t)v.z; o[3] = (bf16_t)v.w;
    *(bf16x4v*)(d + off * 4) = o;
}

// ---------------------------------------------------------------------------
// bf16 MFMA GEMM, double-buffered prefetch K-loop (1 barrier/iter).
// C(M,N) = A(M,K) @ W(N,K)^T + bias(N). TM=128, TN in {64,128}, BK=32.
// MODE: 0 = fp32 out, 1 = bf16 out, 2 = qkv head-layout epilogue:
//   Q pre-scaled by 0.125*log2e; K natural [b,h,s,d]; V transposed [b,h,d,s]
//   with KEY-SLOT PERMUTATION: value of key s is stored at slot
//   swap_bits_2_3(s). This makes the attn PV A-fragment layout equal to the
//   QK^T MFMA's natural S^T output layout -> P never leaves registers in
//   attn (no LDS roundtrip, no permlane). The swap is an involution and
//   preserves bits 0-1, so R5's dword pairing (16 lines/instr) survives.
// R6 lesson pinned: 256^2-tile GEMM2 = 192 blocks on 256 CUs (25% idle) +
// 1 block/CU -> regressed 10us. 128^2 (768 blocks, 2/CU) is the optimum here.
// ---------------------------------------------------------------------------
template<int TN, int MODE>
__global__ __launch_bounds__(256) void gemm_bt_bf16(
    const bf16_t* __restrict__ A, const bf16_t* __restrict__ W,
    const float* __restrict__ bias, void* __restrict__ Cout,
    bf16_t* __restrict__ Qp, bf16_t* __restrict__ Kp, bf16_t* __restrict__ Vtp,
    int M, int N, int K)
{
    constexpr int MB = (TN == 128) ? 4 : 2;
    __shared__ __align__(16) bf16_t As[2][128 * 32];
    __shared__ __align__(16) bf16_t Bs[2][TN * 32];

    const int tid  = threadIdx.x;
    const int lane = tid & 63;
    const int w    = tid >> 6;
    const int lm   = lane & 15;
    const int lq   = lane >> 4;
    const long m0  = (long)blockIdx.y * 128;
    const long n0  = (long)blockIdx.x * TN;
    const int wm0  = (TN == 128) ? (w >> 1) * 64 : w * 32;
    const int wn0  = (TN == 128) ? (w & 1) * 64 : 0;

    f32x4 acc[MB][4];
#pragma unroll
    for (int i = 0; i < MB; ++i)
#pragma unroll
        for (int j = 0; j < 4; ++j) acc[i][j] = (f32x4){0.f, 0.f, 0.f, 0.f};

    auto stage = [&](int k0, int buf) {
        bf16_t* asb = &As[buf][0];
        bf16_t* bsb = &Bs[buf][0];
#pragma unroll
        for (int j = 0; j < 2; ++j) {
            int a   = (w * 2 + j) * 64 + lane;
            int row = a >> 2;
            int c   = (a & 3) ^ ((row >> 1) & 3);
            g2l16(A + (m0 + row) * K + k0 + c * 8, asb + (w * 2 + j) * 512);
        }
#pragma unroll
        for (int j = 0; j < TN / 64; ++j) {
            int a   = (w * (TN / 64) + j) * 64 + lane;
            int row = a >> 2;
            int c   = (a & 3) ^ ((row >> 1) & 3);
            g2l16(W + (n0 + row) * K + k0 + c * 8, bsb + (w * (TN / 64) + j) * 512);
        }
    };

    stage(0, 0);
    for (int k0 = 0; k0 < K; k0 += 32) {
        const int cur = (k0 >> 5) & 1;
        asm volatile("s_waitcnt vmcnt(0)" ::: "memory");
        __syncthreads();
        if (k0 + 32 < K) stage(k0 + 32, cur ^ 1);

        bf16x8 af[MB], bfr[4];
#pragma unroll
        for (int mb = 0; mb < MB; ++mb) {
            int r = wm0 + mb * 16 + lm;
            af[mb] = *(const bf16x8*)&As[cur][r * 32 + ((lq ^ ((r >> 1) & 3)) << 3)];
        }
#pragma unroll
        for (int nb = 0; nb < 4; ++nb) {
            int r = wn0 + nb * 16 + lm;
            bfr[nb] = *(const bf16x8*)&Bs[cur][r * 32 + ((lq ^ ((r >> 1) & 3)) << 3)];
        }
#pragma unroll
        for (int mb = 0; mb < MB; ++mb)
#pragma unroll
            for (int nb = 0; nb < 4; ++nb)
                acc[mb][nb] = __builtin_amdgcn_mfma_f32_16x16x32_bf16(
                    af[mb], bfr[nb], acc[mb][nb], 0, 0, 0);
    }

    // ---- epilogue ----
    float b4[4];
#pragma unroll
    for (int nb = 0; nb < 4; ++nb) b4[nb] = bias[n0 + wn0 + nb * 16 + lm];

    if (MODE == 2) {
#pragma unroll
        for (int mb = 0; mb < MB; ++mb) {
            const long mbase = m0 + wm0 + mb * 16 + lq * 4;   // even
#pragma unroll
            for (int nb = 0; nb < 4; ++nb) {
                int n    = (int)n0 + wn0 + nb * 16 + lm;
                int sec  = n >> 10;
                int nloc = n & 1023;
                int h    = nloc >> 6;
                int d    = nloc & 63;
                if (sec == 2) {
                    // paired Vt store at PERMUTED slot: swap bits 2<->3 of s
                    int s0 = (int)(mbase >> 1);
                    int sp = (s0 & ~12) | ((s0 & 4) << 1) | ((s0 & 8) >> 1);
#pragma unroll
                    for (int rp = 0; rp < 2; ++rp) {
                        int bh = rp * 16 + h;
                        unsigned int pkv = pk2(acc[mb][nb][rp]     + b4[nb],
                                               acc[mb][nb][rp + 2] + b4[nb]);
                        *(unsigned int*)&Vtp[((size_t)(bh * 64 + d)) * S_LEN + sp] = pkv;
                    }
                } else {
#pragma unroll
                    for (int r = 0; r < 4; ++r) {
                        long m  = mbase + r;
                        int  s  = (int)(m >> 1), b = (int)(m & 1);
                        int  bh = b * 16 + h;
                        float v = acc[mb][nb][r] + b4[nb];
                        if (sec == 0) {
                            Qp[((size_t)(bh * S_LEN + s)) * 64 + d] =
                                (bf16_t)(v * (0.125f * L2E));
                        } else {
                            Kp[((size_t)(bh * S_LEN + s)) * 64 + d] = (bf16_t)v;
                        }
                    }
                }
            }
        }
    } else {
#pragma unroll
        for (int mb = 0; mb < MB; ++mb) {
#pragma unroll
            for (int r = 0; r < 4; ++r) {
                long m = m0 + wm0 + mb * 16 + lq * 4 + r;
#pragma unroll
                for (int nb = 0; nb < 4; ++nb) {
                    int n   = (int)n0 + wn0 + nb * 16 + lm;
                    float v = acc[mb][nb][r] + b4[nb];
                    if (MODE == 0) ((float*)Cout)[m * N + n] = v;
                    else           ((bf16_t*)Cout)[m * N + n] = (bf16_t)v;
                }
            }
        }
    }
}

// ---------------------------------------------------------------------------
// MFMA flash attention — R3 structure (256 thr / 4 waves / 32 iters / 2
// blocks per CU, coalesced staging + XOR slot(row,c)=row*8+(c^(row&7)) K/V
// layout, XCD bh swizzle, setprio) with R7's IN-REGISTER P:
//   Vt's key rows are stored bit-2/3-swapped (GEMM2 epilogue), which makes
//   the PV A-fragment equal an in-lane repack of the QK^T output:
//     pf[ks][e] = bf16(exp2(sacc[ks>>1][(e&3) + 8*(ks&1) + 4*(e>>2)]))
//   -> P LDS roundtrip (8 b64 writes + 8 b64 reads + lgkm serialization per
//   iter) deleted; LDS traffic -33%; 16 KB LDS freed; zero added VALU.
// Pinned lessons: R1 in-reg-P via permlane slower (serial VALU); R2
// key-split slower; R4 64q/wave (1 wave/SIMD) much slower; 2 blocks/CU min.
// ---------------------------------------------------------------------------
__global__ __launch_bounds__(256, 2) void attn_mfma(
    const bf16_t* __restrict__ Qb, const bf16_t* __restrict__ Kb,
    const bf16_t* __restrict__ Vtb, bf16_t* __restrict__ O)
{
    __shared__ __align__(16) bf16_t Ks[2][8 * 512];    // 16 KB, swizzled rows
    __shared__ __align__(16) bf16_t Vts[2][8 * 512];   // 16 KB, swizzled rows
    __shared__ __align__(16) float  Lw4[4][32];        // per-wave row sums

    const int tid  = threadIdx.x;
    const int lane = tid & 63;
    const int w    = tid >> 6;
    const int bid  = blockIdx.x;
    // XCD swizzle: XCD x gets blocks {x, x+8, ...} = 4 consecutive bh
    const int bh   = ((bid & 7) << 2) | (bid >> 7);
    const int qt   = (bid >> 3) & 15;
    const int l5   = lane & 31;
    const int hi   = lane >> 5;

    // staging lane geometry: row-within-8-group + inverse-swizzled chunk
    const int rsub = lane >> 3;                  // 0..7
    const int csw  = (lane & 7) ^ rsub;          // chunk this lane fetches
    // fragment-read swizzled chunk offsets (elements), per-lane constant
    int cc[4];
#pragma unroll
    for (int i = 0; i < 4; ++i) cc[i] = ((2 * i + hi) ^ (l5 & 7)) * 8;

    // Q B-frags (B[n=q][k=d]), q = qt*128 + w*32 + l5, held in regs
    const bf16_t* qrow = Qb + ((size_t)bh * S_LEN + qt * 128 + w * 32 + l5) * 64 + hi * 8;
    bf16x8 qf[4];
#pragma unroll
    for (int ds = 0; ds < 4; ++ds) qf[ds] = *(const bf16x8*)(qrow + ds * 16);

    f32x16 oacc[2];
#pragma unroll
    for (int dh = 0; dh < 2; ++dh)
#pragma unroll
        for (int i = 0; i < 16; ++i) oacc[dh][i] = 0.f;
    float plsum = 0.f;

    // coalesced staging: instr i covers rows 8i..8i+7, LDS bytes [1024i,1024i+1024)
    auto stageKV = [&](int kt, int buf) {
        bf16_t* ksb = &Ks[buf][0];
        bf16_t* vsb = &Vts[buf][0];
        const bf16_t* kg = Kb + ((size_t)bh * S_LEN + kt * 64) * 64;
        const bf16_t* vg = Vtb + (size_t)bh * 64 * S_LEN + kt * 64;
#pragma unroll
        for (int j = 0; j < 2; ++j) {
            int i = w * 2 + j;
            g2l16(kg + (size_t)(i * 8 + rsub) * 64 + csw * 8,    ksb + i * 512);
            g2l16(vg + (size_t)(i * 8 + rsub) * S_LEN + csw * 8, vsb + i * 512);
        }
    };

    stageKV(0, 0);
    for (int kt = 0; kt < 32; ++kt) {
        const int cur = kt & 1;
        asm volatile("s_waitcnt vmcnt(0)" ::: "memory");
        __syncthreads();
        if (kt < 31) stageKV(kt + 1, cur ^ 1);

        // ---- S^T = K·Q^T per key half (log2 domain) ----
        f32x16 sacc[2];
        __builtin_amdgcn_s_setprio(1);
#pragma unroll
        for (int kh = 0; kh < 2; ++kh) {
#pragma unroll
            for (int i = 0; i < 16; ++i) sacc[kh][i] = 0.f;
#pragma unroll
            for (int ds = 0; ds < 4; ++ds) {
                bf16x8 kf = *(const bf16x8*)&Ks[cur][(kh * 32 + l5) * 64 + cc[ds]];
                sacc[kh] = __builtin_amdgcn_mfma_f32_32x32x16_bf16(kf, qf[ds], sacc[kh], 0, 0, 0);
            }
        }
        __builtin_amdgcn_s_setprio(0);

        // ---- toroidal bias: only near-diagonal K-tiles ----
        int ktd = (kt - 2 * qt) & 31;
        if (ktd <= 2 || ktd == 31) {
            int q = qt * 128 + w * 32 + l5;
#pragma unroll
            for (int kh = 0; kh < 2; ++kh)
#pragma unroll
                for (int r = 0; r < 16; ++r) {
                    int key  = kt * 64 + kh * 32 + (r & 3) + 8 * (r >> 2) + 4 * hi;
                    int diff = (key - q) & (S_LEN - 1);
                    if (diff <= 1 || diff == S_LEN - 1) sacc[kh][r] += L2E;
                }
        }

        // ---- p = 2^S, all in registers ----
        float pv[2][16];
#pragma unroll
        for (int kh = 0; kh < 2; ++kh)
#pragma unroll
            for (int i = 0; i < 16; ++i) {
                pv[kh][i] = __builtin_amdgcn_exp2f(sacc[kh][i]);
                plsum += pv[kh][i];
            }

        // ---- PV A-frags: pure in-lane repack (V rows are bit-2/3-swapped) ----
        bf16x8 pf[4];
#pragma unroll
        for (int ks = 0; ks < 4; ++ks) {
            const int kh = ks >> 1, m = ks & 1;
#pragma unroll
            for (int e = 0; e < 8; ++e)
                pf[ks][e] = (bf16_t)pv[kh][(e & 3) + 8 * m + 4 * (e >> 2)];
        }

        // ---- PV: O[q][d] += P·V ----
        __builtin_amdgcn_s_setprio(1);
#pragma unroll
        for (int dh = 0; dh < 2; ++dh) {
#pragma unroll
            for (int ks = 0; ks < 4; ++ks) {
                bf16x8 vf = *(const bf16x8*)&Vts[cur][(dh * 32 + l5) * 64 + cc[ks]];
                oacc[dh] = __builtin_amdgcn_mfma_f32_32x32x16_bf16(pf[ks], vf, oacc[dh], 0, 0, 0);
            }
        }
        __builtin_amdgcn_s_setprio(0);
    }

    // ---- l: lane + lane^32 hold the two key-halves of row q=l5 ----
    plsum += __shfl_xor(plsum, 32, 64);
    if (hi == 0) Lw4[w][l5] = plsum;

    float inv16[16];
#pragma unroll
    for (int g = 0; g < 4; ++g) {
        f32x4 lv = *(const f32x4*)&Lw4[w][8 * g + 4 * hi];
#pragma unroll
        for (int e = 0; e < 4; ++e) inv16[g * 4 + e] = 1.0f / lv[e];
    }

    const int b = bh >> 4, h = bh & 15;
#pragma unroll
    for (int dh = 0; dh < 2; ++dh)
#pragma unroll
        for (int r = 0; r < 16; ++r) {
            int qrel = (r & 3) + 8 * (r >> 2) + 4 * hi;
            int s = qt * 128 + w * 32 + qrel;
            O[((size_t)(s * NB + b)) * EMB + h * 64 + dh * 32 + l5] =
                (bf16_t)(oacc[dh][r] * inv16[r]);
        }
}

// ---------------------------------------------------------------------------
// Workspace map (42 MB):
//   [ 0, 8) xb -> reused as Qb | [ 8,10) wtorb | [10,16) ipwb | [16,18) outwb
//   [18,26) xtb -> reused as Ob | [26,34) Kb | [34,42) Vtb (permuted cols)
// ---------------------------------------------------------------------------
extern "C" void kernel_launch(void* const* d_in, const int* in_sizes, int n_in,
                              void* d_out, int out_size, void* d_ws, size_t ws_size,
                              hipStream_t stream)
{
    const float* x         = (const float*)d_in[0];
    const float* w_tor     = (const float*)d_in[1];
    const float* b_tor     = (const float*)d_in[2];
    const float* in_proj_w = (const float*)d_in[3];
    const float* in_proj_b = (const float*)d_in[4];
    const float* out_w     = (const float*)d_in[5];
    const float* out_b     = (const float*)d_in[6];
    float* out = (float*)d_out;

    const int M = S_LEN * NB;   // 4096

    char* base = (char*)d_ws;
    bf16_t* xb    = (bf16_t*)(base);
    bf16_t* wtorb = (bf16_t*)(base + ( 8ull << 20));
    bf16_t* ipwb  = (bf16_t*)(base + (10ull << 20));
    bf16_t* outwb = (bf16_t*)(base + (16ull << 20));
    bf16_t* xtb   = (bf16_t*)(base + (18ull << 20));
    bf16_t* Kb    = (bf16_t*)(base + (26ull << 20));
    bf16_t* Vtb   = (bf16_t*)(base + (34ull << 20));
    bf16_t* Qb    = xb;    // alias: xb dead once GEMM1 has run
    bf16_t* Ob    = xtb;   // alias: xtb dead once GEMM2 has run

    cast4_f32_bf16<<<dim3(9216), 256, 0, stream>>>(
        x, xb, w_tor, wtorb, in_proj_w, ipwb, out_w, outwb);

    gemm_bt_bf16<64, 1><<<dim3(EMB / 64, M / 128), 256, 0, stream>>>(
        xb, wtorb, b_tor, xtb, nullptr, nullptr, nullptr, M, EMB, EMB);

    gemm_bt_bf16<128, 2><<<dim3(3 * EMB / 128, M / 128), 256, 0, stream>>>(
        xtb, ipwb, in_proj_b, nullptr, Qb, Kb, Vtb, M, 3 * EMB, EMB);

    attn_mfma<<<dim3(32 * 16), 256, 0, stream>>>(Qb, Kb, Vtb, Ob);

    gemm_bt_bf16<64, 0><<<dim3(EMB / 64, M / 128), 256, 0, stream>>>(
        Ob, outwb, out_b, out, nullptr, nullptr, nullptr, M, EMB, EMB);
}